// Round 1
// 176.901 us; speedup vs baseline: 1.1057x; 1.1057x over previous
//
#include <hip/hip_runtime.h>

#define N_NODES 100000
#define N_EDGES 1600000
#define D 64
#define H 128
#define SCAN_BS 512
#define SCAN_NBLK ((N_NODES + SCAN_BS - 1) / SCAN_BS)   // 196

// bucket pipeline
#define NB 1563                  // buckets of 64 nodes: 1563*64 >= 100000
#define NCHUNK 256
#define EPC (N_EDGES / NCHUNK)   // 6250 exactly
#define BCAP 2560                // LDS edge cap per bucket (avg 1024)
#define OVF_CAP 4096

#define MFMA_GRID 768            // 3 blocks/CU x 256 CU with ~50KB LDS
#define SH_STRIDE 132            // fp32 fallback MLP
#define SH16_ST 136              // bf16 sh stride (16B-aligned rows)

typedef __attribute__((ext_vector_type(8))) short short8;
typedef __attribute__((ext_vector_type(4))) float floatx4;
typedef __attribute__((ext_vector_type(4))) unsigned short ushort4_t;
typedef __attribute__((ext_vector_type(8))) unsigned short ushort8_t;

__device__ __forceinline__ unsigned short f2bf(float f) {
    unsigned u = __builtin_bit_cast(unsigned, f);
    u += 0x7FFFu + ((u >> 16) & 1u);
    return (unsigned short)(u >> 16);
}
__device__ __forceinline__ float bf2f(unsigned short u) {
    unsigned v = ((unsigned)u) << 16;
    return __builtin_bit_cast(float, v);
}

// ===========================================================================
__global__ __launch_bounds__(256) void k_zero(int* __restrict__ p, int n) {
    int i = blockIdx.x * 256 + threadIdx.x;
    if (i < n) p[i] = 0;
}

// ===========================================================================
// P0 fused: blocks [0,NCHUNK): per-chunk bucket histogram -> M2 (coalesced).
//           block NCHUNK:     W1 -> bf16 MFMA-layout gW1b
//           block NCHUNK+1:   W2 -> bf16 MFMA-layout gW2b
//           rest:             x fp32 -> x16 bf16 (grid-stride)
// ===========================================================================
__global__ __launch_bounds__(256) void k_pre(const float4* __restrict__ x4,
                                             ushort4_t* __restrict__ y, int n4,
                                             const int* __restrict__ dst,
                                             int* __restrict__ M2,
                                             int* __restrict__ ovfn,
                                             const float* __restrict__ W1,
                                             const float* __restrict__ W2,
                                             unsigned short* __restrict__ gW1b,
                                             unsigned short* __restrict__ gW2b) {
    __shared__ int hist[NB];
    int t = threadIdx.x, blk = blockIdx.x;
    if (blk < NCHUNK) {
        int c = blk;
        if (c == 0 && t == 0) ovfn[0] = 0;
        for (int i = t; i < NB; i += 256) hist[i] = 0;
        __syncthreads();
        const int* dp = dst + c * EPC;
        for (int i = t; i < EPC; i += 256) atomicAdd(&hist[dp[i] >> 6], 1);
        __syncthreads();
        int* mp = M2 + c * NB;
        for (int i = t; i < NB; i += 256) mp[i] = hist[i];
    } else if (blk == NCHUNK) {
        for (int q = t; q < 8192; q += 256) {
            int j = q & 7, l = (q >> 3) & 63, f = q >> 9;
            int nt = f & 7, kt = f >> 3;
            int k = kt * 32 + ((l >> 4) << 3) + j;
            int n = nt * 16 + (l & 15);
            gW1b[q] = f2bf(W1[k * H + n]);
        }
    } else if (blk == NCHUNK + 1) {
        for (int q = t; q < 8192; q += 256) {
            int j = q & 7, l = (q >> 3) & 63, f = q >> 9;
            int nt = f & 3, kt = f >> 2;
            int k = kt * 32 + ((l >> 4) << 3) + j;
            int n = nt * 16 + (l & 15);
            gW2b[q] = f2bf(W2[k * D + n]);
        }
    } else {
        int cb = blk - NCHUNK - 2;
        int nconv = gridDim.x - NCHUNK - 2;
        for (int i = cb * 256 + t; i < n4; i += nconv * 256) {
            float4 v = x4[i];
            ushort4_t o;
            o[0] = f2bf(v.x); o[1] = f2bf(v.y); o[2] = f2bf(v.z); o[3] = f2bf(v.w);
            y[i] = o;
        }
    }
}

// ===========================================================================
// S1: column-wise exclusive scan of M2, coalesced (thread per bucket-column).
// ===========================================================================
__global__ __launch_bounds__(256) void k_colscan(int* __restrict__ M2,
                                                 int* __restrict__ colsum) {
    int b = blockIdx.x * 256 + threadIdx.x;
    if (b >= NB) return;
    int run = 0;
    for (int c = 0; c < NCHUNK; c++) {
        int v = M2[c * NB + b];
        M2[c * NB + b] = run;
        run += v;
    }
    colsum[b] = run;
}

// ===========================================================================
// S2: single-block inclusive scan of colsum[NB] -> bends[NB].
// ===========================================================================
__global__ __launch_bounds__(512) void k_bscan(const int* __restrict__ colsum,
                                               int* __restrict__ bends) {
    __shared__ int part[512];
    int t = threadIdx.x;
    int i0 = t * 4;
    int v0 = (i0 + 0 < NB) ? colsum[i0 + 0] : 0;
    int v1 = (i0 + 1 < NB) ? colsum[i0 + 1] : 0;
    int v2 = (i0 + 2 < NB) ? colsum[i0 + 2] : 0;
    int v3 = (i0 + 3 < NB) ? colsum[i0 + 3] : 0;
    int r0 = v0, r1 = r0 + v1, r2 = r1 + v2, r3 = r2 + v3;
    part[t] = r3;
    __syncthreads();
    for (int off = 1; off < 512; off <<= 1) {
        int u = (t >= off) ? part[t - off] : 0;
        __syncthreads();
        part[t] += u;
        __syncthreads();
    }
    int base = (t > 0) ? part[t - 1] : 0;
    if (i0 + 0 < NB) bends[i0 + 0] = base + r0;
    if (i0 + 1 < NB) bends[i0 + 1] = base + r1;
    if (i0 + 2 < NB) bends[i0 + 2] = base + r2;
    if (i0 + 3 < NB) bends[i0 + 3] = base + r3;
}

// ===========================================================================
// P3: partition edges into bucket-ordered ebuf, packed (dlow<<17)|src.
// ===========================================================================
__global__ __launch_bounds__(256) void k_part(const int* __restrict__ src,
                                              const int* __restrict__ dst,
                                              const int* __restrict__ M2,
                                              const int* __restrict__ bends,
                                              int* __restrict__ ebuf) {
    __shared__ int cur[NB];
    int t = threadIdx.x, c = blockIdx.x;
    const int* mp = M2 + c * NB;
    for (int i = t; i < NB; i += 256)
        cur[i] = ((i > 0) ? bends[i - 1] : 0) + mp[i];
    __syncthreads();
    const int* sp = src + c * EPC;
    const int* dp = dst + c * EPC;
    for (int i = t; i < EPC; i += 256) {
        int d = dp[i], s = sp[i];
        int p = atomicAdd(&cur[d >> 6], 1);
        ebuf[p] = s | ((d & 63) << 17);
    }
}

// ===========================================================================
// P4: one block per bucket. Mini-CSR in LDS, then EIGHTH-WAVE PER NODE
// register-accum gather: 8 lanes/node, each lane owns 8 features and loads
// 16B (dwordx4) per edge -> half the VMEM instructions of the 16-lane/8B
// variant, half the serial edge depth (2 nodes/group). Epilogue adds fp32 x
// and writes bf16 out16 directly (bit-identical to the old fp32-out + f2bf
// in the MLP, but saves the 25.6MB fp32 round-trip).
// ===========================================================================
__global__ __launch_bounds__(256) void k_bagg4(const float* __restrict__ x,
                                               const unsigned short* __restrict__ x16,
                                               const int* __restrict__ ebuf,
                                               const int* __restrict__ bends,
                                               int* __restrict__ ovfn,
                                               int* __restrict__ ovf,
                                               unsigned short* __restrict__ o16) {
    __shared__ int scur[64];
    __shared__ int snd[64];          // inclusive ends per dlow
    __shared__ int slist[BCAP];
    int t = threadIdx.x, b = blockIdx.x;
    int estart = (b > 0) ? bends[b - 1] : 0;
    int ne = bends[b] - estart;
    const int* ep = ebuf + estart;

    if (t < 64) scur[t] = 0;
    __syncthreads();
    for (int i = t; i < ne; i += 256) atomicAdd(&scur[ep[i] >> 17], 1);
    __syncthreads();
    if (t < 64) {
        int v = scur[t], s = v;
#pragma unroll
        for (int off = 1; off < 64; off <<= 1) {
            int u = __shfl_up(s, off, 64);
            if (t >= off) s += u;
        }
        snd[t] = s;
        scur[t] = s - v;             // exclusive start -> cursor
    }
    __syncthreads();
    for (int i = t; i < ne; i += 256) {
        int v = ep[i];
        int p = atomicAdd(&scur[v >> 17], 1);
        if (p < BCAP) {
            slist[p] = v & 0x1FFFF;
        } else {                     // practically never (Poisson(1024))
            int o = atomicAdd(ovfn, 1);
            if (o < OVF_CAP) { ovf[2 * o] = b * 64 + (v >> 17); ovf[2 * o + 1] = v & 0x1FFFF; }
        }
    }
    __syncthreads();

    int g = t >> 3;                  // eighth-wave group 0..31
    int l8 = t & 7;                  // feature octet: feats l8*8 .. l8*8+7
#pragma unroll
    for (int k = 0; k < 2; k++) {
        int dlow = g * 2 + k;
        int node = b * 64 + dlow;
        int s0 = (dlow > 0) ? snd[dlow - 1] : 0;
        int e1 = snd[dlow];
        if (s0 > BCAP) s0 = BCAP;
        if (e1 > BCAP) e1 = BCAP;    // clipped edges live in ovf
        float accA[8], accB[8];
#pragma unroll
        for (int j = 0; j < 8; j++) { accA[j] = 0.f; accB[j] = 0.f; }
        int i = s0;
        for (; i + 4 <= e1; i += 4) {
            int sA = slist[i], sB = slist[i + 1], sC = slist[i + 2], sD = slist[i + 3];
            ushort8_t uA = *(const ushort8_t*)&x16[(size_t)sA * D + l8 * 8];
            ushort8_t uB = *(const ushort8_t*)&x16[(size_t)sB * D + l8 * 8];
            ushort8_t uC = *(const ushort8_t*)&x16[(size_t)sC * D + l8 * 8];
            ushort8_t uD = *(const ushort8_t*)&x16[(size_t)sD * D + l8 * 8];
#pragma unroll
            for (int j = 0; j < 8; j++) accA[j] += bf2f(uA[j]);
#pragma unroll
            for (int j = 0; j < 8; j++) accB[j] += bf2f(uB[j]);
#pragma unroll
            for (int j = 0; j < 8; j++) accA[j] += bf2f(uC[j]);
#pragma unroll
            for (int j = 0; j < 8; j++) accB[j] += bf2f(uD[j]);
        }
        for (; i < e1; i++) {
            int sA = slist[i];
            ushort8_t uA = *(const ushort8_t*)&x16[(size_t)sA * D + l8 * 8];
#pragma unroll
            for (int j = 0; j < 8; j++) accA[j] += bf2f(uA[j]);
        }
        if (node < N_NODES) {
            const float* xp = x + (size_t)node * D + l8 * 8;
            float4 x0 = *(const float4*)xp;
            float4 x1 = *(const float4*)(xp + 4);
            ushort8_t o;
            o[0] = f2bf(accA[0] + accB[0] + x0.x);
            o[1] = f2bf(accA[1] + accB[1] + x0.y);
            o[2] = f2bf(accA[2] + accB[2] + x0.z);
            o[3] = f2bf(accA[3] + accB[3] + x0.w);
            o[4] = f2bf(accA[4] + accB[4] + x1.x);
            o[5] = f2bf(accA[5] + accB[5] + x1.y);
            o[6] = f2bf(accA[6] + accB[6] + x1.z);
            o[7] = f2bf(accA[7] + accB[7] + x1.w);
            *(ushort8_t*)&o16[(size_t)node * D + l8 * 8] = o;
        }
    }
}

// overflow cleanup on bf16 out16 (normally *ovfn == 0). Single wave, serial
// over entries: lane f owns feature f -> no races.
__global__ __launch_bounds__(64) void k_ovf(const int* __restrict__ ovfn,
                                            const int* __restrict__ ovf,
                                            const float* __restrict__ x,
                                            unsigned short* __restrict__ o16) {
    int n = *ovfn;
    if (n > OVF_CAP) n = OVF_CAP;
    int f = threadIdx.x;
    for (int idx = 0; idx < n; idx++) {
        int d = ovf[2 * idx], s = ovf[2 * idx + 1];
        unsigned short* p = &o16[(size_t)d * D + f];
        *p = f2bf(bf2f(*p) + x[(size_t)s * D + f]);
    }
}

// ===========================================================================
// MFMA bf16 fused MLP, Tier-A: reads bf16 in16 (direct short8 A-loads, no
// conversions), bf16 LDS h-staging (LDS ~50KB -> 3 blocks/CU), writes fp32
// final output. Weights pre-converted to MFMA layout in workspace.
// ===========================================================================
__global__ __launch_bounds__(256) void k_mlp16(const unsigned short* __restrict__ in16,
                                               float* __restrict__ outp,
                                               const unsigned short* __restrict__ gW1b,
                                               const unsigned short* __restrict__ gW2b,
                                               const float* __restrict__ b1,
                                               const float* __restrict__ b2) {
    __shared__ unsigned short sW1b[8192];
    __shared__ unsigned short sW2b[8192];
    __shared__ unsigned short sh16[4][16 * SH16_ST];
    __shared__ float sb1[H];
    __shared__ float sb2[D];

    int t = threadIdx.x;
    for (int q = t; q < 1024; q += 256) {
        *(short8*)&sW1b[q * 8] = *(const short8*)&gW1b[q * 8];
        *(short8*)&sW2b[q * 8] = *(const short8*)&gW2b[q * 8];
    }
    if (t < H) sb1[t] = b1[t];
    if (t >= H && t < H + D) sb2[t - H] = b2[t - H];
    __syncthreads();

    int w = t >> 6, l = t & 63;
    int m = l & 15, q4 = l >> 4;
    unsigned short* shw = sh16[w];

    const int NT16 = N_NODES / 16;
    const int WAVES = MFMA_GRID * 4;
    const int ITERS = (NT16 + WAVES - 1) / WAVES;

    for (int it = 0; it < ITERS; ++it) {
        int tl = it * WAVES + blockIdx.x * 4 + w;
        bool valid = tl < NT16;
        int nbase = tl * 16;

        if (valid) {
            const unsigned short* xr = in16 + (size_t)(nbase + m) * D + q4 * 8;
            short8 A0 = *(const short8*)(xr);
            short8 A1 = *(const short8*)(xr + 32);

#pragma unroll
            for (int nt = 0; nt < 8; nt++) {
                float bv = sb1[nt * 16 + m];
                floatx4 acc = {bv, bv, bv, bv};
                short8 B0 = *(const short8*)&sW1b[(0 * 8 + nt) * 512 + l * 8];
                short8 B1 = *(const short8*)&sW1b[(1 * 8 + nt) * 512 + l * 8];
                acc = __builtin_amdgcn_mfma_f32_16x16x32_bf16(A0, B0, acc, 0, 0, 0);
                acc = __builtin_amdgcn_mfma_f32_16x16x32_bf16(A1, B1, acc, 0, 0, 0);
#pragma unroll
                for (int r = 0; r < 4; r++)
                    shw[(q4 * 4 + r) * SH16_ST + nt * 16 + m] = f2bf(fmaxf(acc[r], 0.f));
            }
        }
        __syncthreads();

        if (valid) {
            short8 Ah[4];
#pragma unroll
            for (int kt = 0; kt < 4; kt++)
                Ah[kt] = *(const short8*)&shw[m * SH16_ST + kt * 32 + q4 * 8];
#pragma unroll
            for (int nt = 0; nt < 4; nt++) {
                float bv = sb2[nt * 16 + m];
                floatx4 acc = {bv, bv, bv, bv};
#pragma unroll
                for (int kt = 0; kt < 4; kt++) {
                    short8 B = *(const short8*)&sW2b[(kt * 4 + nt) * 512 + l * 8];
                    acc = __builtin_amdgcn_mfma_f32_16x16x32_bf16(Ah[kt], B, acc, 0, 0, 0);
                }
#pragma unroll
                for (int r = 0; r < 4; r++)
                    outp[(size_t)(nbase + q4 * 4 + r) * D + nt * 16 + m] = acc[r];
            }
        }
        __syncthreads();
    }
}

// ===========================================================================
// fp32 in-place MFMA MLP — Tier-B/C fallback only (original R6-proven).
// ===========================================================================
__global__ __launch_bounds__(256) void k_mlp_f32(float* __restrict__ io,
                                                 const float* __restrict__ W1,
                                                 const float* __restrict__ b1,
                                                 const float* __restrict__ W2,
                                                 const float* __restrict__ b2) {
    __shared__ unsigned short sW1b[8192];
    __shared__ unsigned short sW2b[8192];
    __shared__ float sh[4][16 * SH_STRIDE];
    __shared__ float sb1[H];
    __shared__ float sb2[D];

    int t = threadIdx.x;

    for (int q = t; q < 8192; q += 256) {
        int j = q & 7, l = (q >> 3) & 63, f = q >> 9;
        int nt = f & 7, kt = f >> 3;
        int k = kt * 32 + ((l >> 4) << 3) + j;
        int n = nt * 16 + (l & 15);
        sW1b[q] = f2bf(W1[k * H + n]);
    }
    for (int q = t; q < 8192; q += 256) {
        int j = q & 7, l = (q >> 3) & 63, f = q >> 9;
        int nt = f & 3, kt = f >> 2;
        int k = kt * 32 + ((l >> 4) << 3) + j;
        int n = nt * 16 + (l & 15);
        sW2b[q] = f2bf(W2[k * D + n]);
    }
    if (t < H) sb1[t] = b1[t];
    if (t >= H && t < H + D) sb2[t - H] = b2[t - H];
    __syncthreads();

    int w = t >> 6, l = t & 63;
    int m = l & 15, q4 = l >> 4;
    float* shw = sh[w];

    const int NT16 = N_NODES / 16;
    const int WAVES = 512 * 4;
    const int ITERS = (NT16 + WAVES - 1) / WAVES;

    for (int it = 0; it < ITERS; ++it) {
        int tl = it * WAVES + blockIdx.x * 4 + w;
        bool valid = tl < NT16;
        int nbase = tl * 16;

        if (valid) {
            const float* xr = io + (size_t)(nbase + m) * D + q4 * 8;
            float4 a0 = *(const float4*)(xr);
            float4 a1 = *(const float4*)(xr + 4);
            float4 c0 = *(const float4*)(xr + 32);
            float4 c1 = *(const float4*)(xr + 36);
            short8 A0, A1;
            A0[0] = f2bf(a0.x); A0[1] = f2bf(a0.y); A0[2] = f2bf(a0.z); A0[3] = f2bf(a0.w);
            A0[4] = f2bf(a1.x); A0[5] = f2bf(a1.y); A0[6] = f2bf(a1.z); A0[7] = f2bf(a1.w);
            A1[0] = f2bf(c0.x); A1[1] = f2bf(c0.y); A1[2] = f2bf(c0.z); A1[3] = f2bf(c0.w);
            A1[4] = f2bf(c1.x); A1[5] = f2bf(c1.y); A1[6] = f2bf(c1.z); A1[7] = f2bf(c1.w);

#pragma unroll
            for (int nt = 0; nt < 8; nt++) {
                float bv = sb1[nt * 16 + m];
                floatx4 acc = {bv, bv, bv, bv};
                short8 B0 = *(const short8*)&sW1b[(0 * 8 + nt) * 512 + l * 8];
                short8 B1 = *(const short8*)&sW1b[(1 * 8 + nt) * 512 + l * 8];
                acc = __builtin_amdgcn_mfma_f32_16x16x32_bf16(A0, B0, acc, 0, 0, 0);
                acc = __builtin_amdgcn_mfma_f32_16x16x32_bf16(A1, B1, acc, 0, 0, 0);
#pragma unroll
                for (int r = 0; r < 4; r++)
                    shw[(q4 * 4 + r) * SH_STRIDE + nt * 16 + m] = fmaxf(acc[r], 0.f);
            }
        }
        __syncthreads();

        if (valid) {
            short8 Ah[4];
#pragma unroll
            for (int kt = 0; kt < 4; kt++) {
                const float* hr = &shw[m * SH_STRIDE + kt * 32 + q4 * 8];
                float4 h0 = *(const float4*)(hr);
                float4 h1 = *(const float4*)(hr + 4);
                Ah[kt][0] = f2bf(h0.x); Ah[kt][1] = f2bf(h0.y);
                Ah[kt][2] = f2bf(h0.z); Ah[kt][3] = f2bf(h0.w);
                Ah[kt][4] = f2bf(h1.x); Ah[kt][5] = f2bf(h1.y);
                Ah[kt][6] = f2bf(h1.z); Ah[kt][7] = f2bf(h1.w);
            }
#pragma unroll
            for (int nt = 0; nt < 4; nt++) {
                float bv = sb2[nt * 16 + m];
                floatx4 acc = {bv, bv, bv, bv};
#pragma unroll
                for (int kt = 0; kt < 4; kt++) {
                    short8 B = *(const short8*)&sW2b[(kt * 4 + nt) * 512 + l * 8];
                    acc = __builtin_amdgcn_mfma_f32_16x16x32_bf16(Ah[kt], B, acc, 0, 0, 0);
                }
#pragma unroll
                for (int r = 0; r < 4; r++)
                    io[(size_t)(nbase + q4 * 4 + r) * D + nt * 16 + m] = acc[r];
            }
        }
        __syncthreads();
    }
}

// ===========================================================================
// parametric inclusive scan (3 phases) — Tier-B fallback only
// ===========================================================================
__global__ __launch_bounds__(SCAN_BS) void k_scan1(const int* __restrict__ cnt,
                                                   int* __restrict__ ends,
                                                   int* __restrict__ bsum, int n) {
    __shared__ int s[SCAN_BS];
    int t = threadIdx.x, b = blockIdx.x;
    int id = b * SCAN_BS + t;
    s[t] = (id < n) ? cnt[id] : 0;
    __syncthreads();
    for (int off = 1; off < SCAN_BS; off <<= 1) {
        int u = (t >= off) ? s[t - off] : 0;
        __syncthreads();
        s[t] += u;
        __syncthreads();
    }
    if (id < n) ends[id] = s[t];
    if (t == SCAN_BS - 1) bsum[b] = s[t];
}

__global__ __launch_bounds__(256) void k_scan2(int* __restrict__ bsum, int nb) {
    __shared__ int s[256];
    int t = threadIdx.x;
    s[t] = (t < nb) ? bsum[t] : 0;
    __syncthreads();
    for (int off = 1; off < 256; off <<= 1) {
        int u = (t >= off) ? s[t - off] : 0;
        __syncthreads();
        s[t] += u;
        __syncthreads();
    }
    if (t < nb) bsum[t] = s[t];
}

__global__ __launch_bounds__(SCAN_BS) void k_scan3(int* __restrict__ ends,
                                                   const int* __restrict__ bsum, int n) {
    int t = threadIdx.x, b = blockIdx.x;
    int id = b * SCAN_BS + t;
    if (b > 0 && id < n) ends[id] += bsum[b - 1];
}

__global__ __launch_bounds__(256) void k_histpos(const int* __restrict__ dst,
                                                 int* __restrict__ cnt,
                                                 int* __restrict__ pos) {
    int e = blockIdx.x * 256 + threadIdx.x;
    if (e < N_EDGES) pos[e] = atomicAdd(&cnt[dst[e]], 1);
}

__global__ __launch_bounds__(256) void k_fill2(const int* __restrict__ src,
                                               const int* __restrict__ dst,
                                               const int* __restrict__ pos,
                                               const int* __restrict__ ends,
                                               int* __restrict__ csr) {
    int e = blockIdx.x * 256 + threadIdx.x;
    if (e >= N_EDGES) return;
    int d = dst[e];
    int start = (d > 0) ? ends[d - 1] : 0;
    csr[start + pos[e]] = src[e];
}

__global__ __launch_bounds__(256) void k_agg(const float* __restrict__ x,
                                             const int* __restrict__ csr,
                                             const int* __restrict__ ends,
                                             float* __restrict__ out) {
    int node = blockIdx.x * 4 + (threadIdx.x >> 6);
    if (node >= N_NODES) return;
    int f = threadIdx.x & 63;
    int start = (node > 0) ? ends[node - 1] : 0;
    int end = ends[node];
    float a0 = x[(size_t)node * D + f], a1 = 0.f, a2 = 0.f, a3 = 0.f;
    int e = start;
    for (; e + 4 <= end; e += 4) {
        int s0 = csr[e], s1 = csr[e + 1], s2 = csr[e + 2], s3 = csr[e + 3];
        a0 += x[(size_t)s0 * D + f];
        a1 += x[(size_t)s1 * D + f];
        a2 += x[(size_t)s2 * D + f];
        a3 += x[(size_t)s3 * D + f];
    }
    for (; e < end; e++) a0 += x[(size_t)csr[e] * D + f];
    out[(size_t)node * D + f] = (a0 + a1) + (a2 + a3);
}

// ===========================================================================
// Tier-C fallback: atomic scatter (R2-proven)
// ===========================================================================
__global__ __launch_bounds__(256) void k_init(const float4* __restrict__ x4,
                                              float4* __restrict__ agg4, int n4) {
    int i = blockIdx.x * 256 + threadIdx.x;
    if (i < n4) agg4[i] = x4[i];
}

__global__ __launch_bounds__(256) void k_scatter(const float4* __restrict__ x4,
                                                 const int* __restrict__ src,
                                                 const int* __restrict__ dst,
                                                 float* __restrict__ agg) {
    int gid = blockIdx.x * 256 + threadIdx.x;
    int e = gid >> 4;
    if (e >= N_EDGES) return;
    int c = gid & 15;
    float4 v = x4[src[e] * 16 + c];
    float* p = agg + (size_t)dst[e] * D + c * 4;
    atomicAdd(p + 0, v.x);
    atomicAdd(p + 1, v.y);
    atomicAdd(p + 2, v.z);
    atomicAdd(p + 3, v.w);
}

// ===========================================================================
extern "C" void kernel_launch(void* const* d_in, const int* in_sizes, int n_in,
                              void* d_out, int out_size, void* d_ws, size_t ws_size,
                              hipStream_t stream) {
    const float* x  = (const float*)d_in[0];
    const int* eidx = (const int*)d_in[1];   // [2, N_EDGES] int32 per harness
    const float* W1 = (const float*)d_in[2];
    const float* b1 = (const float*)d_in[3];
    const float* W2 = (const float*)d_in[4];
    const float* b2 = (const float*)d_in[5];
    float* out      = (float*)d_out;

    const int* src = eidx;
    const int* dst = eidx + N_EDGES;

    int ge = (N_EDGES + 255) / 256;
    int n4 = N_NODES * D / 4;

    // Tier A: x16[N*D bf16] o16[N*D bf16] ebuf[E] M2[NCHUNK*NB] colsum[NB]
    //         bends[NB] ovfn[4] ovf[2*OVF_CAP] gW1b[8192] gW2b[8192]  ~= 33.7 MB
    size_t need_A = (size_t)N_NODES * D * 2 * sizeof(unsigned short)
                  + (size_t)(N_EDGES + NCHUNK * NB + 2 * NB + 4 + 2 * OVF_CAP) * sizeof(int)
                  + (size_t)16384 * sizeof(unsigned short);
    // Tier B: cnt[N] ends[N] bsum[512] pos[E] csr[E] (~13.6 MB)
    size_t need_B = (size_t)(2 * N_NODES + 512 + 2 * N_EDGES) * sizeof(int);

    if (ws_size >= need_A) {
        unsigned short* x16 = (unsigned short*)d_ws;
        unsigned short* o16 = x16 + (size_t)N_NODES * D;
        int* ebuf   = (int*)(o16 + (size_t)N_NODES * D);
        int* M2     = ebuf + N_EDGES;
        int* colsum = M2 + NCHUNK * NB;
        int* bends  = colsum + NB;
        int* ovfn   = bends + NB;
        int* ovf    = ovfn + 4;
        unsigned short* gW1b = (unsigned short*)(ovf + 2 * OVF_CAP);
        unsigned short* gW2b = gW1b + 8192;

        k_pre<<<NCHUNK + 2 + 2048, 256, 0, stream>>>((const float4*)x, (ushort4_t*)x16, n4,
                                                     dst, M2, ovfn, W1, W2, gW1b, gW2b);
        k_colscan<<<(NB + 255) / 256, 256, 0, stream>>>(M2, colsum);
        k_bscan<<<1, 512, 0, stream>>>(colsum, bends);
        k_part<<<NCHUNK, 256, 0, stream>>>(src, dst, M2, bends, ebuf);
        k_bagg4<<<NB, 256, 0, stream>>>(x, x16, ebuf, bends, ovfn, ovf, o16);
        k_ovf<<<1, 64, 0, stream>>>(ovfn, ovf, x, o16);
        k_mlp16<<<MFMA_GRID, 256, 0, stream>>>(o16, out, gW1b, gW2b, b1, b2);
    } else if (ws_size >= need_B) {
        int* cnt  = (int*)d_ws;
        int* ends = cnt + N_NODES;
        int* bsum = ends + N_NODES;
        int* pos  = bsum + 512;
        int* csr  = pos + N_EDGES;

        k_zero<<<(N_NODES + 255) / 256, 256, 0, stream>>>(cnt, N_NODES);
        k_histpos<<<ge, 256, 0, stream>>>(dst, cnt, pos);
        k_scan1<<<SCAN_NBLK, SCAN_BS, 0, stream>>>(cnt, ends, bsum, N_NODES);
        k_scan2<<<1, 256, 0, stream>>>(bsum, SCAN_NBLK);
        k_scan3<<<SCAN_NBLK, SCAN_BS, 0, stream>>>(ends, bsum, N_NODES);
        k_fill2<<<ge, 256, 0, stream>>>(src, dst, pos, ends, csr);
        k_agg<<<(N_NODES + 3) / 4, 256, 0, stream>>>(x, csr, ends, out);
        k_mlp_f32<<<512, 256, 0, stream>>>(out, W1, b1, W2, b2);
    } else {
        k_init<<<(n4 + 255) / 256, 256, 0, stream>>>((const float4*)x, (float4*)out, n4);
        long long total = (long long)N_EDGES * 16;
        k_scatter<<<(int)((total + 255) / 256), 256, 0, stream>>>(
            (const float4*)x, src, dst, out);
        k_mlp_f32<<<512, 256, 0, stream>>>(out, W1, b1, W2, b2);
    }
}